// Round 1
// baseline (4693.343 us; speedup 1.0000x reference)
//
#include <hip/hip_runtime.h>

#define N_NODES 100000
#define N_EDGES 1600000
#define IN_F 128
#define HID_F 64
#define OUT_F 40
#define N_STEPS 10

static constexpr float DT = 0.1f;
// SIGMA * sqrt(DT) = 0.01 * sqrt(0.1)
static constexpr float C_NOISE = 0.0031622776601683794f;

// ---------------- degree histogram ----------------
__global__ __launch_bounds__(256) void deg_kernel(const int* __restrict__ src,
                                                  const int* __restrict__ dst,
                                                  float* __restrict__ deg_out,
                                                  float* __restrict__ deg_in) {
    int i = blockIdx.x * 256 + threadIdx.x;
    if (i < N_EDGES) {
        atomicAdd(&deg_out[src[i]], 1.0f);
        atomicAdd(&deg_in[dst[i]], 1.0f);
    }
}

// ---------------- per-edge norm ----------------
__global__ __launch_bounds__(256) void norm_kernel(const int* __restrict__ src,
                                                   const int* __restrict__ dst,
                                                   const float* __restrict__ deg_out,
                                                   const float* __restrict__ deg_in,
                                                   float* __restrict__ norm) {
    int i = blockIdx.x * 256 + threadIdx.x;
    if (i < N_EDGES) {
        float dq = fmaxf(deg_out[src[i]], 1.0f);
        float dk = fmaxf(deg_in[dst[i]], 1.0f);
        norm[i] = rsqrtf(dq) * rsqrtf(dk);
    }
}

// ---------------- row GEMM: Y[n,64] = A[n,K] @ W[K,64] ----------------
// Block = 256 threads = 4 rows x 64 cols. W staged in LDS.
template <int K>
__global__ __launch_bounds__(256) void rowmm64_kernel(const float* __restrict__ A,
                                                      const float* __restrict__ W,
                                                      float* __restrict__ Y,
                                                      int n_rows) {
    __shared__ float w[K * HID_F];
    for (int i = threadIdx.x; i < K * HID_F; i += 256) w[i] = W[i];
    __syncthreads();

    int r = blockIdx.x * 4 + (threadIdx.x >> 6);
    int j = threadIdx.x & 63;
    if (r >= n_rows) return;

    const float* ar = A + (size_t)r * K;
    float acc = 0.0f;
#pragma unroll
    for (int k = 0; k < K; k += 4) {
        float4 av = *reinterpret_cast<const float4*>(ar + k);
        acc += av.x * w[(k + 0) * HID_F + j];
        acc += av.y * w[(k + 1) * HID_F + j];
        acc += av.z * w[(k + 2) * HID_F + j];
        acc += av.w * w[(k + 3) * HID_F + j];
    }
    Y[(size_t)r * HID_F + j] = acc;
}

// ---------------- edge scatter: agg[dst] += m[src] * norm ----------------
// one thread per (edge, feature); 64 lanes of a wave share one edge.
__global__ __launch_bounds__(256) void scatter_kernel(const float* __restrict__ m,
                                                      const float* __restrict__ norm,
                                                      const int* __restrict__ src,
                                                      const int* __restrict__ dst,
                                                      float* __restrict__ agg) {
    int i = blockIdx.x * 256 + threadIdx.x;  // < E*64 = 102.4M < 2^31
    int e = i >> 6;
    int f = i & 63;
    if (e >= N_EDGES) return;
    int s = src[e];
    int d = dst[e];
    float v = m[(size_t)s * HID_F + f] * norm[e];
    atomicAdd(&agg[(size_t)d * HID_F + f], v);
}

// ---------------- Euler-Maruyama update ----------------
// x = (1-DT)*x + DT*agg + C_NOISE*dW_k   (float4-vectorized)
__global__ __launch_bounds__(256) void update_kernel(float* __restrict__ x,
                                                     const float* __restrict__ agg,
                                                     const float* __restrict__ dw) {
    int i = blockIdx.x * 256 + threadIdx.x;
    const int n4 = N_NODES * HID_F / 4;
    if (i >= n4) return;
    float4 xv = reinterpret_cast<const float4*>(x)[i];
    float4 av = reinterpret_cast<const float4*>(agg)[i];
    float4 wv = reinterpret_cast<const float4*>(dw)[i];
    const float a = 1.0f - DT;
    xv.x = a * xv.x + DT * av.x + C_NOISE * wv.x;
    xv.y = a * xv.y + DT * av.y + C_NOISE * wv.y;
    xv.z = a * xv.z + DT * av.z + C_NOISE * wv.z;
    xv.w = a * xv.w + DT * av.w + C_NOISE * wv.w;
    reinterpret_cast<float4*>(x)[i] = xv;
}

// ---------------- out projection: out[n,40] = x[n,64] @ W_out[64,40] ----------------
__global__ __launch_bounds__(256) void out_proj_kernel(const float* __restrict__ x,
                                                       const float* __restrict__ W,
                                                       float* __restrict__ out) {
    __shared__ float w[HID_F * OUT_F];
    for (int i = threadIdx.x; i < HID_F * OUT_F; i += 256) w[i] = W[i];
    __syncthreads();

    int i = blockIdx.x * 256 + threadIdx.x;  // over N*40 = 4M
    if (i >= N_NODES * OUT_F) return;
    int r = i / OUT_F;
    int j = i - r * OUT_F;
    const float* xr = x + (size_t)r * HID_F;
    float acc = 0.0f;
#pragma unroll
    for (int k = 0; k < HID_F; k++) acc += xr[k] * w[k * OUT_F + j];
    out[i] = acc;
}

extern "C" void kernel_launch(void* const* d_in, const int* in_sizes, int n_in,
                              void* d_out, int out_size, void* d_ws, size_t ws_size,
                              hipStream_t stream) {
    const float* h     = (const float*)d_in[0];
    const float* W_in  = (const float*)d_in[1];
    const float* W_msg = (const float*)d_in[2];
    const float* W_out = (const float*)d_in[3];
    const float* dW    = (const float*)d_in[4];
    const int*   src   = (const int*)d_in[5];
    const int*   dst   = (const int*)d_in[6];
    float* out = (float*)d_out;

    const size_t NH = (size_t)N_NODES * HID_F;  // 6.4M
    float* x    = (float*)d_ws;
    float* m    = x + NH;
    float* agg  = m + NH;
    float* norm = agg + NH;
    float* dego = norm + N_EDGES;
    float* degi = dego + N_NODES;

    // degrees + norm
    hipMemsetAsync(dego, 0, 2 * N_NODES * sizeof(float), stream);
    {
        dim3 g((N_EDGES + 255) / 256);
        deg_kernel<<<g, 256, 0, stream>>>(src, dst, dego, degi);
        norm_kernel<<<g, 256, 0, stream>>>(src, dst, dego, degi, norm);
    }

    // x = h @ W_in
    rowmm64_kernel<IN_F><<<dim3((N_NODES + 3) / 4), 256, 0, stream>>>(h, W_in, x, N_NODES);

    // 10 Euler-Maruyama steps
    const dim3 g_scatter((N_EDGES * 64 + 255) / 256);   // 400000 blocks
    const dim3 g_mm((N_NODES + 3) / 4);
    const dim3 g_upd((N_NODES * HID_F / 4 + 255) / 256);
    for (int k = 0; k < N_STEPS; k++) {
        rowmm64_kernel<HID_F><<<g_mm, 256, 0, stream>>>(x, W_msg, m, N_NODES);
        hipMemsetAsync(agg, 0, NH * sizeof(float), stream);
        scatter_kernel<<<g_scatter, 256, 0, stream>>>(m, norm, src, dst, agg);
        update_kernel<<<g_upd, 256, 0, stream>>>(x, agg, dW + (size_t)k * NH);
    }

    // out = x @ W_out
    out_proj_kernel<<<dim3((N_NODES * OUT_F + 255) / 256), 256, 0, stream>>>(x, W_out, out);
}

// Round 2
// 1792.857 us; speedup vs baseline: 2.6178x; 2.6178x over previous
//
#include <hip/hip_runtime.h>

#define N_NODES 100000
#define N_EDGES 1600000
#define IN_F 128
#define HID_F 64
#define OUT_F 40
#define N_STEPS 10

static constexpr float DT = 0.1f;
// SIGMA * sqrt(DT) = 0.01 * sqrt(0.1)
static constexpr float C_NOISE = 0.0031622776601683794f;

// ---------------- degree histograms (int) ----------------
__global__ __launch_bounds__(256) void deg_kernel(const int* __restrict__ src,
                                                  const int* __restrict__ dst,
                                                  int* __restrict__ deg_out,
                                                  int* __restrict__ deg_in) {
    int i = blockIdx.x * 256 + threadIdx.x;
    if (i < N_EDGES) {
        atomicAdd(&deg_out[src[i]], 1);
        atomicAdd(&deg_in[dst[i]], 1);
    }
}

// ---------------- per-node scale factors ----------------
// a[i] = rsqrt(max(deg_out,1)) ; b[i] = rsqrt(max(deg_in,1))
__global__ __launch_bounds__(256) void scale_kernel(const int* __restrict__ deg_out,
                                                    const int* __restrict__ deg_in,
                                                    float* __restrict__ a,
                                                    float* __restrict__ b) {
    int i = blockIdx.x * 256 + threadIdx.x;
    if (i < N_NODES) {
        a[i] = rsqrtf((float)max(deg_out[i], 1));
        b[i] = rsqrtf((float)max(deg_in[i], 1));
    }
}

// ---------------- 3-kernel exclusive scan of deg_in -> row_ptr ----------------
__global__ __launch_bounds__(256) void scan_blocksum_kernel(const int* __restrict__ deg,
                                                            int* __restrict__ blocksum) {
    __shared__ int buf[256];
    int i = blockIdx.x * 256 + threadIdx.x;
    buf[threadIdx.x] = (i < N_NODES) ? deg[i] : 0;
    __syncthreads();
    for (int off = 128; off > 0; off >>= 1) {
        if (threadIdx.x < off) buf[threadIdx.x] += buf[threadIdx.x + off];
        __syncthreads();
    }
    if (threadIdx.x == 0) blocksum[blockIdx.x] = buf[0];
}

// single block: exclusive scan of up to 512 block sums
__global__ __launch_bounds__(512) void scan_top_kernel(const int* __restrict__ blocksum,
                                                       int* __restrict__ blockpfx,
                                                       int nblocks) {
    __shared__ int buf[512];
    int v = (threadIdx.x < nblocks) ? blocksum[threadIdx.x] : 0;
    buf[threadIdx.x] = v;
    __syncthreads();
    for (int off = 1; off < 512; off <<= 1) {
        int t = (threadIdx.x >= off) ? buf[threadIdx.x - off] : 0;
        __syncthreads();
        buf[threadIdx.x] += t;
        __syncthreads();
    }
    if (threadIdx.x < nblocks) blockpfx[threadIdx.x] = buf[threadIdx.x] - v;
}

__global__ __launch_bounds__(256) void scan_final_kernel(const int* __restrict__ deg,
                                                         const int* __restrict__ blockpfx,
                                                         int* __restrict__ row_ptr,
                                                         int* __restrict__ cursor) {
    __shared__ int buf[256];
    int i = blockIdx.x * 256 + threadIdx.x;
    int v = (i < N_NODES) ? deg[i] : 0;
    buf[threadIdx.x] = v;
    __syncthreads();
    for (int off = 1; off < 256; off <<= 1) {
        int t = (threadIdx.x >= off) ? buf[threadIdx.x - off] : 0;
        __syncthreads();
        buf[threadIdx.x] += t;
        __syncthreads();
    }
    int excl = blockpfx[blockIdx.x] + buf[threadIdx.x] - v;
    if (i < N_NODES) {
        row_ptr[i] = excl;
        cursor[i] = excl;
    }
    if (blockIdx.x == gridDim.x - 1 && threadIdx.x == 255)
        row_ptr[N_NODES] = blockpfx[blockIdx.x] + buf[255];
}

// ---------------- CSR fill: bucket edges by dst ----------------
__global__ __launch_bounds__(256) void fill_kernel(const int* __restrict__ src,
                                                   const int* __restrict__ dst,
                                                   int* __restrict__ cursor,
                                                   int* __restrict__ src_sorted) {
    int e = blockIdx.x * 256 + threadIdx.x;
    if (e < N_EDGES) {
        int pos = atomicAdd(&cursor[dst[e]], 1);
        src_sorted[pos] = src[e];
    }
}

// ---------------- row GEMM: Y[n,64] = (A[n,K] @ W[K,64]) * scale[n]? ----------------
// Block = 256 threads = 4 rows x 64 cols. W staged in LDS.
template <int K, bool SCALE>
__global__ __launch_bounds__(256) void rowmm64_kernel(const float* __restrict__ A,
                                                      const float* __restrict__ W,
                                                      float* __restrict__ Y,
                                                      const float* __restrict__ scale) {
    __shared__ float w[K * HID_F];
    for (int i = threadIdx.x; i < K * HID_F; i += 256) w[i] = W[i];
    __syncthreads();

    int r = blockIdx.x * 4 + (threadIdx.x >> 6);
    int j = threadIdx.x & 63;
    if (r >= N_NODES) return;

    const float* ar = A + (size_t)r * K;
    float acc = 0.0f;
#pragma unroll
    for (int k = 0; k < K; k += 4) {
        float4 av = *reinterpret_cast<const float4*>(ar + k);
        acc += av.x * w[(k + 0) * HID_F + j];
        acc += av.y * w[(k + 1) * HID_F + j];
        acc += av.z * w[(k + 2) * HID_F + j];
        acc += av.w * w[(k + 3) * HID_F + j];
    }
    if (SCALE) acc *= scale[r];
    Y[(size_t)r * HID_F + j] = acc;
}

// ---------------- fused gather + Euler-Maruyama update ----------------
// one wave (64 lanes) per dst node; lane = feature.
// x[d] = 0.9*x[d] + 0.1*b[d]*sum_{e in CSR[d]} m[src_e] + C_NOISE*dW[d]
__global__ __launch_bounds__(256) void gather_update_kernel(const float* __restrict__ m,
                                                            const int* __restrict__ row_ptr,
                                                            const int* __restrict__ src_sorted,
                                                            const float* __restrict__ b,
                                                            float* __restrict__ x,
                                                            const float* __restrict__ dw) {
    int d = blockIdx.x * 4 + (threadIdx.x >> 6);
    int lane = threadIdx.x & 63;
    if (d >= N_NODES) return;

    int beg = row_ptr[d];
    int end = row_ptr[d + 1];

    float acc0 = 0.f, acc1 = 0.f, acc2 = 0.f, acc3 = 0.f;
    int j = beg;
    while (j < end) {
        int cnt = min(end - j, 64);
        int idx = (lane < cnt) ? src_sorted[j + lane] : 0;
        int jj = 0;
        for (; jj + 4 <= cnt; jj += 4) {
            int s0 = __shfl(idx, jj + 0);
            int s1 = __shfl(idx, jj + 1);
            int s2 = __shfl(idx, jj + 2);
            int s3 = __shfl(idx, jj + 3);
            acc0 += m[(size_t)s0 * HID_F + lane];
            acc1 += m[(size_t)s1 * HID_F + lane];
            acc2 += m[(size_t)s2 * HID_F + lane];
            acc3 += m[(size_t)s3 * HID_F + lane];
        }
        for (; jj < cnt; ++jj) {
            int s = __shfl(idx, jj);
            acc0 += m[(size_t)s * HID_F + lane];
        }
        j += cnt;
    }
    float acc = (acc0 + acc1) + (acc2 + acc3);

    size_t o = (size_t)d * HID_F + lane;
    float xv = x[o];
    x[o] = (1.0f - DT) * xv + (DT * b[d]) * acc + C_NOISE * dw[o];
}

// ---------------- out projection: out[n,40] = x[n,64] @ W_out[64,40] ----------------
__global__ __launch_bounds__(256) void out_proj_kernel(const float* __restrict__ x,
                                                       const float* __restrict__ W,
                                                       float* __restrict__ out) {
    __shared__ float w[HID_F * OUT_F];
    for (int i = threadIdx.x; i < HID_F * OUT_F; i += 256) w[i] = W[i];
    __syncthreads();

    int i = blockIdx.x * 256 + threadIdx.x;  // over N*40 = 4M
    if (i >= N_NODES * OUT_F) return;
    int r = i / OUT_F;
    int j = i - r * OUT_F;
    const float* xr = x + (size_t)r * HID_F;
    float acc = 0.0f;
#pragma unroll
    for (int k = 0; k < HID_F; k++) acc += xr[k] * w[k * OUT_F + j];
    out[i] = acc;
}

extern "C" void kernel_launch(void* const* d_in, const int* in_sizes, int n_in,
                              void* d_out, int out_size, void* d_ws, size_t ws_size,
                              hipStream_t stream) {
    const float* h     = (const float*)d_in[0];
    const float* W_in  = (const float*)d_in[1];
    const float* W_msg = (const float*)d_in[2];
    const float* W_out = (const float*)d_in[3];
    const float* dW    = (const float*)d_in[4];
    const int*   src   = (const int*)d_in[5];
    const int*   dst   = (const int*)d_in[6];
    float* out = (float*)d_out;

    const size_t NH = (size_t)N_NODES * HID_F;  // 6.4M
    const int NBLK = (N_NODES + 255) / 256;     // 391

    float* x       = (float*)d_ws;              // 6.4M f
    float* m       = x + NH;                    // 6.4M f
    float* a       = m + NH;                    // 100K f
    float* b       = a + N_NODES;               // 100K f
    int* deg_out_i = (int*)(b + N_NODES);       // 100K i
    int* deg_in_i  = deg_out_i + N_NODES;       // 100K i
    int* row_ptr   = deg_in_i + N_NODES;        // 100K+1 i
    int* cursor    = row_ptr + N_NODES + 1;     // 100K+1 i
    int* blocksum  = cursor + N_NODES + 1;      // 391 i
    int* blockpfx  = blocksum + 512;            // 391 i
    int* src_sorted= blockpfx + 512;            // 1.6M i

    // ---- one-time per launch: degrees, scales, CSR ----
    hipMemsetAsync(deg_out_i, 0, 2 * N_NODES * sizeof(int), stream);
    {
        dim3 ge((N_EDGES + 255) / 256);
        deg_kernel<<<ge, 256, 0, stream>>>(src, dst, deg_out_i, deg_in_i);
        scale_kernel<<<dim3(NBLK), 256, 0, stream>>>(deg_out_i, deg_in_i, a, b);
        scan_blocksum_kernel<<<dim3(NBLK), 256, 0, stream>>>(deg_in_i, blocksum);
        scan_top_kernel<<<1, 512, 0, stream>>>(blocksum, blockpfx, NBLK);
        scan_final_kernel<<<dim3(NBLK), 256, 0, stream>>>(deg_in_i, blockpfx, row_ptr, cursor);
        fill_kernel<<<ge, 256, 0, stream>>>(src, dst, cursor, src_sorted);
    }

    // ---- x = h @ W_in ----
    rowmm64_kernel<IN_F, false><<<dim3((N_NODES + 3) / 4), 256, 0, stream>>>(h, W_in, x, nullptr);

    // ---- 10 Euler-Maruyama steps ----
    const dim3 g_node((N_NODES + 3) / 4);
    for (int k = 0; k < N_STEPS; k++) {
        // m = (x @ W_msg) * rsqrt(deg_out)
        rowmm64_kernel<HID_F, true><<<g_node, 256, 0, stream>>>(x, W_msg, m, a);
        // x = 0.9 x + 0.1 * b * gather(m) + C_NOISE * dW_k
        gather_update_kernel<<<g_node, 256, 0, stream>>>(m, row_ptr, src_sorted, b, x,
                                                         dW + (size_t)k * NH);
    }

    // ---- out = x @ W_out ----
    out_proj_kernel<<<dim3((N_NODES * OUT_F + 255) / 256), 256, 0, stream>>>(x, W_out, out);
}